// Round 1
// baseline (318.181 us; speedup 1.0000x reference)
//
#include <hip/hip_runtime.h>

#define S_LEN 8192
#define C_CTX 21
#define E_DIM 128
#define G_DIM 36
#define H_DIM 1024
#define T_TAG 32
#define D_RAW 3444          // 21*(128+36)
#define DP 3456             // padded to multiple of 64 (54 K-tiles of 64)
#define START_TAG 30
#define STOP_TAG 31
#define NEGV -10000.0f
#define K_CHUNKS 64
#define L_CHUNK 128         // K_CHUNKS * L_CHUNK == S_LEN

typedef __bf16 bf16_t;
typedef __bf16 bf16x4 __attribute__((ext_vector_type(4)));
typedef __bf16 bf16x8 __attribute__((ext_vector_type(8)));
typedef float  f32x4  __attribute__((ext_vector_type(4)));

__device__ inline void async_copy16(const bf16_t* g, bf16_t* l) {
    __builtin_amdgcn_global_load_lds(
        (const __attribute__((address_space(1))) void*)g,
        (__attribute__((address_space(3))) void*)l, 16, 0, 0);
}

// ---------------- Phase 0: materialize padded bf16 X and W1 ----------------
// 4 cols per thread: 164 = 41 groups of 4; groups never straddle emb/gz.
__global__ void build_x(const int* __restrict__ ctx, const float* __restrict__ gz,
                        const float* __restrict__ emb, bf16_t* __restrict__ X) {
    const int s = blockIdx.x;
    for (int g = threadIdx.x; g < DP / 4; g += 256) {   // 864 groups
        float4 v = {0.f, 0.f, 0.f, 0.f};
        if (g < D_RAW / 4) {                             // 861 real groups
            const int c  = g / 41;
            const int rg = g - c * 41;                   // 0..40
            if (rg < 32) v = *(const float4*)&emb[(size_t)ctx[s * C_CTX + c] * E_DIM + rg * 4];
            else         v = *(const float4*)&gz[((size_t)s * C_CTX + c) * G_DIM + (rg - 32) * 4];
        }
        bf16x4 o = {(bf16_t)v.x, (bf16_t)v.y, (bf16_t)v.z, (bf16_t)v.w};
        *(bf16x4*)&X[(size_t)s * DP + g * 4] = o;
    }
}

__global__ void build_w1b(const float* __restrict__ w1, bf16_t* __restrict__ W) {
    const int h = blockIdx.x;
    for (int g = threadIdx.x; g < DP / 4; g += 256) {
        float4 v = {0.f, 0.f, 0.f, 0.f};
        if (g < D_RAW / 4) v = *(const float4*)&w1[(size_t)h * D_RAW + g * 4];
        bf16x4 o = {(bf16_t)v.x, (bf16_t)v.y, (bf16_t)v.z, (bf16_t)v.w};
        *(bf16x4*)&W[(size_t)h * DP + g * 4] = o;
    }
}

// ---------------- Phase 1: h = relu(X @ W1^T + b1), bf16 MFMA -------------
// 256x128 tile, BK=64, 512 threads (8 waves, 4M x 2N, 64x64 per wave).
// Triple-buffered K-tile pipeline: prefetch distance 2, counted vmcnt(6)
// at the rotation barrier (T4) — next tile's 6 loads stay in flight across
// the barrier. Stage issues spread across the 4 compute quadrants (T3-lite),
// setprio around each MFMA cluster (T5).
// LDS k-group swizzle kg ^ (row&7): inverse-swizzled global source + linear
// global_load_lds dest + swizzled ds_read (both-sides-or-neither).
__global__ __launch_bounds__(512) void gemm1(const bf16_t* __restrict__ X,
                                             const bf16_t* __restrict__ W,
                                             const float* __restrict__ b1,
                                             bf16_t* __restrict__ Hout) {
    __shared__ bf16_t As[3][256 * 64];   // 3 x 32 KB
    __shared__ bf16_t Bs[3][128 * 64];   // 3 x 16 KB  (total 144 KB)
    const int tid  = threadIdx.x;
    const int wave = tid >> 6, lane = tid & 63;
    const int s0 = blockIdx.x * 256, h0 = blockIdx.y * 128;
    const int wm = (wave >> 1) * 64;     // 4 wave-rows
    const int wn = (wave & 1) * 64;      // 2 wave-cols

    // staging: load l = i*512+tid -> LDS row l/8 = i*64 + (tid>>3), group tid&7
    // source k-group inverse-swizzled so that LDS[row][g] = X[row][(g^(row&7))*8..]
    const int arow = tid >> 3;                         // 0..63
    const int akg  = (tid & 7) ^ (arow & 7);
    const bf16_t* gA = X + (size_t)(s0 + arow) * DP + akg * 8;
    const bf16_t* gB = W + (size_t)(h0 + arow) * DP + akg * 8;

    const int lrow  = lane & 15;
    const int khalf = lane >> 4;         // 0..3
    const int lr7   = lrow & 7;

#define STAGE_A(buf, k0, i) async_copy16(gA + (size_t)(i) * 64 * DP + (k0), &As[buf][((i) * 512 + tid) * 8])
#define STAGE_B(buf, k0, i) async_copy16(gB + (size_t)(i) * 64 * DP + (k0), &Bs[buf][((i) * 512 + tid) * 8])

    // prologue: tiles 0 and 1 (12 loads in flight)
    STAGE_A(0, 0, 0); STAGE_A(0, 0, 1); STAGE_A(0, 0, 2); STAGE_A(0, 0, 3);
    STAGE_B(0, 0, 0); STAGE_B(0, 0, 1);
    STAGE_A(1, 64, 0); STAGE_A(1, 64, 1); STAGE_A(1, 64, 2); STAGE_A(1, 64, 3);
    STAGE_B(1, 64, 0); STAGE_B(1, 64, 1);

    f32x4 acc[4][4] = {};
    const int NT = DP / 64;              // 54
    int rb = 0;
    for (int t = 0; t < NT; ++t) {
        // tile t's 6 loads complete; tile t+1's 6 remain in flight (never drain
        // to 0 in the main loop — T4). Last iteration has nothing behind it.
        if (t + 1 < NT) asm volatile("s_waitcnt vmcnt(6)" ::: "memory");
        else            asm volatile("s_waitcnt vmcnt(0)" ::: "memory");
        __builtin_amdgcn_s_barrier();
        __builtin_amdgcn_sched_barrier(0);
        asm volatile("" ::: "memory");

        const int  sb = (rb == 0) ? 2 : rb - 1;   // == (t+2)%3, buffer of tile t-1
        const int  k2 = (t + 2) * 64;
        const bool st = (t + 2) < NT;

#pragma unroll
        for (int q = 0; q < 4; ++q) {
            // spread next-next tile's stage issues across the quadrants
            if (st) {
                if (q == 0) { STAGE_A(sb, k2, 0); STAGE_A(sb, k2, 1); }
                if (q == 1) { STAGE_A(sb, k2, 2); STAGE_A(sb, k2, 3); }
                if (q == 2) { STAGE_B(sb, k2, 0); STAGE_B(sb, k2, 1); }
            }
            const int qm = q >> 1, qn = q & 1;
            bf16x8 a[2][2], bq[2][2];
#pragma unroll
            for (int ks = 0; ks < 2; ++ks) {
                const int kgr = ((ks * 4 + khalf) ^ lr7) * 8;
#pragma unroll
                for (int mt = 0; mt < 2; ++mt)
                    a[ks][mt] = *(const bf16x8*)&As[rb][(wm + qm * 32 + mt * 16 + lrow) * 64 + kgr];
#pragma unroll
                for (int nt = 0; nt < 2; ++nt)
                    bq[ks][nt] = *(const bf16x8*)&Bs[rb][(wn + qn * 32 + nt * 16 + lrow) * 64 + kgr];
            }
            __builtin_amdgcn_s_setprio(1);
#pragma unroll
            for (int ks = 0; ks < 2; ++ks)
#pragma unroll
                for (int mt = 0; mt < 2; ++mt)
#pragma unroll
                    for (int nt = 0; nt < 2; ++nt)
                        acc[qm * 2 + mt][qn * 2 + nt] = __builtin_amdgcn_mfma_f32_16x16x32_bf16(
                            a[ks][mt], bq[ks][nt], acc[qm * 2 + mt][qn * 2 + nt], 0, 0, 0);
            __builtin_amdgcn_s_setprio(0);
        }
        rb = (rb == 2) ? 0 : rb + 1;
    }
#undef STAGE_A
#undef STAGE_B

    const int crow = (lane >> 4) * 4;
    const int ccol = lane & 15;
#pragma unroll
    for (int nt = 0; nt < 4; ++nt) {
        const int j = h0 + wn + nt * 16 + ccol;
        const float bv = b1[j];
#pragma unroll
        for (int mt = 0; mt < 4; ++mt) {
#pragma unroll
            for (int r = 0; r < 4; ++r) {
                const int s = s0 + wm + mt * 16 + crow + r;
                const float v = acc[mt][nt][r] + bv;
                Hout[(size_t)s * H_DIM + j] = (bf16_t)fmaxf(v, 0.f);
            }
        }
    }
}

// ---------------- Phase 2: feats = H @ w2^T + b2 (fp32 out), MFMA ----------
// M=128 x N=32, BK=64 (16 iters). A via global_load_lds; B converted fp32->bf16
// in-kernel. 64-wide rows: swizzle kg ^ (row&7).
__global__ __launch_bounds__(256) void feats_mfma(const bf16_t* __restrict__ Hb,
                                                  const float* __restrict__ w2,
                                                  const float* __restrict__ b2,
                                                  float* __restrict__ F) {
    __shared__ bf16_t As[128 * 64];
    __shared__ bf16_t Bs[32 * 64];
    const int tid  = threadIdx.x;
    const int wave = tid >> 6, lane = tid & 63;
    const int s0 = blockIdx.x * 128;
    const int wm = wave * 32;

    // A staging: chunk i*256+tid -> row = i*32 + (tid>>3), kg = tid&7
    const int arow = tid >> 3;
    const int akgs = (tid & 7) ^ (arow & 7);          // (i*32+arow)&7 == arow&7
    const bf16_t* gA = Hb + (size_t)(s0 + arow) * H_DIM + akgs * 8;
    // B staging: row = tid>>3 (0..31), kg = tid&7
    const int brow = tid >> 3;
    const int bkgs = (tid & 7) ^ (brow & 7);
    const float* wp = w2 + (size_t)brow * H_DIM + bkgs * 8;
    bf16_t* lB = &Bs[tid * 8];

    const int lrow = lane & 15;

    f32x4 acc[2][2] = {};
    for (int k0 = 0; k0 < H_DIM; k0 += 64) {
#pragma unroll
        for (int i = 0; i < 4; ++i)
            async_copy16(gA + (size_t)i * 32 * H_DIM + k0, &As[(tid + i * 256) * 8]);
        const float4 x0 = *(const float4*)(wp + k0);
        const float4 x1 = *(const float4*)(wp + k0 + 4);
        bf16x8 bb = {(bf16_t)x0.x, (bf16_t)x0.y, (bf16_t)x0.z, (bf16_t)x0.w,
                     (bf16_t)x1.x, (bf16_t)x1.y, (bf16_t)x1.z, (bf16_t)x1.w};
        *(bf16x8*)lB = bb;
        __syncthreads();
#pragma unroll
        for (int ks = 0; ks < 2; ++ks) {
            const int kq = ((ks * 4 + (lane >> 4)) ^ (lrow & 7)) * 8;
            bf16x8 a[2], b[2];
#pragma unroll
            for (int mt = 0; mt < 2; ++mt)
                a[mt] = *(const bf16x8*)&As[(wm + mt * 16 + lrow) * 64 + kq];
#pragma unroll
            for (int nt = 0; nt < 2; ++nt)
                b[nt] = *(const bf16x8*)&Bs[(nt * 16 + lrow) * 64 + kq];
#pragma unroll
            for (int mt = 0; mt < 2; ++mt)
#pragma unroll
                for (int nt = 0; nt < 2; ++nt)
                    acc[mt][nt] = __builtin_amdgcn_mfma_f32_16x16x32_bf16(a[mt], b[nt], acc[mt][nt], 0, 0, 0);
        }
        __syncthreads();
    }
    const int crow = (lane >> 4) * 4;
    const int ccol = lane & 15;
#pragma unroll
    for (int nt = 0; nt < 2; ++nt) {
        const int j = nt * 16 + ccol;
        const float bv = b2[j];
#pragma unroll
        for (int mt = 0; mt < 2; ++mt) {
#pragma unroll
            for (int r = 0; r < 4; ++r) {
                const int s = s0 + wm + mt * 16 + crow + r;
                F[(size_t)s * T_TAG + j] = acc[mt][nt][r] + bv;
            }
        }
    }
}

// ---------------- CRF pass A: per-chunk matrix-chain products --------------
// v round-trips through a per-wave LDS slice (wave-lockstep => barrier-free):
// 1 ds_write + 8 broadcast ds_read_b128 per step instead of 32 bpermutes.
__global__ __launch_bounds__(256) void crfA(const float* __restrict__ F,
                                            const float* __restrict__ trans,
                                            float* __restrict__ QT,
                                            float* __restrict__ sigma) {
    __shared__ float fl[L_CHUNK * 32];
    __shared__ float vb[4][2][32];
    const int c    = blockIdx.x >> 2;
    const int tid  = threadIdx.x;
    const int wave = tid >> 6;
    const int lane = tid & 63;
    const int n    = lane & 31;
    const int pl   = lane >> 5;
    const int p    = ((blockIdx.x & 3) << 3) + (wave << 1) + pl;
    const int s0   = c * L_CHUNK;
    for (int i = tid; i < L_CHUNK * 32; i += 256) fl[i] = F[(size_t)s0 * 32 + i];
    __syncthreads();

    float et[32];
#pragma unroll
    for (int k = 0; k < 32; ++k) et[k] = __expf(trans[n * 32 + k]);

    float* vrow = &vb[wave][pl][0];
    float v  = __expf(trans[n * 32 + p] + fl[n]);
    float sg = 0.f;
    for (int s = 1; s < L_CHUNK; ++s) {
        vrow[n] = v;
        __builtin_amdgcn_s_waitcnt(0xC07F);   // lgkmcnt(0): wave-coherent LDS
        float a0 = 0.f, a1 = 0.f, a2 = 0.f, a3 = 0.f;
#pragma unroll
        for (int q = 0; q < 8; ++q) {
            const float4 wv = *(const float4*)&vrow[q * 4];
            a0 = __builtin_fmaf(et[q * 4 + 0], wv.x, a0);
            a1 = __builtin_fmaf(et[q * 4 + 1], wv.y, a1);
            a2 = __builtin_fmaf(et[q * 4 + 2], wv.z, a2);
            a3 = __builtin_fmaf(et[q * 4 + 3], wv.w, a3);
        }
        v = __expf(fl[s * 32 + n]) * ((a0 + a1) + (a2 + a3));
        if ((s & 7) == 7) {
            float m = v;
#pragma unroll
            for (int off = 16; off; off >>= 1) m = fmaxf(m, __shfl_xor(m, off, 32));
            if (m > 0.f) { v *= 1.0f / m; sg += __logf(m); }
        }
    }
    QT[(c * 32 + p) * 32 + n] = v;
    if (n == 0) sigma[c * 32 + p] = sg;
}

// ---------------- CRF pass B: parallel matrix fold ----------------
__global__ __launch_bounds__(1024) void crf_fold(const float* __restrict__ Qin,
                                                 const float* __restrict__ Sin,
                                                 const int fold, const int final,
                                                 float* __restrict__ Qout,
                                                 float* __restrict__ Sout,
                                                 const float* __restrict__ trans,
                                                 const float* __restrict__ F,
                                                 const int* __restrict__ lab,
                                                 float* __restrict__ out) {
    __shared__ float A[32][33];
    __shared__ float M[32][33];
    __shared__ float sgf[32];
    __shared__ float gred[16];
    __shared__ float gold_s;

    const int t = threadIdx.x;
    const int p = t >> 5, n = t & 31;
    const int c0 = blockIdx.x * fold;

    if (final) {
        float ga = 0.f;
        for (int s = t; s < S_LEN; s += 1024) {
            const int tg = lab[s];
            ga += F[(size_t)s * T_TAG + tg];
            const int tp = (s == 0) ? START_TAG : lab[s - 1];
            ga += trans[tg * T_TAG + tp];
        }
        if (t == 0) ga += trans[STOP_TAG * T_TAG + lab[S_LEN - 1]];
#pragma unroll
        for (int off = 32; off; off >>= 1) ga += __shfl_down(ga, off, 64);
        if ((t & 63) == 0) gred[t >> 6] = ga;
    }

    A[n][p] = Qin[(size_t)(c0 * 32 + p) * 32 + n];
    float sA = Sin[c0 * 32 + p];
    float mreg = Qin[(size_t)((c0 + 1) * 32 + p) * 32 + n];

    for (int i = 1; i < fold; ++i) {
        const float sMn = Sin[(c0 + i) * 32 + n];
        float mmax = sMn;
#pragma unroll
        for (int off = 16; off; off >>= 1) mmax = fmaxf(mmax, __shfl_xor(mmax, off, 32));
        const float sMp = Sin[(c0 + i) * 32 + p];
        __syncthreads();
        M[n][p] = mreg * __expf(sMp - mmax);
        if (i + 1 < fold) mreg = Qin[(size_t)((c0 + i + 1) * 32 + p) * 32 + n];
        __syncthreads();
        float acc = 0.f;
#pragma unroll 8
        for (int k = 0; k < 32; ++k)
            acc += M[n][k] * A[k][p];
        float cm = acc;
#pragma unroll
        for (int off = 16; off; off >>= 1) cm = fmaxf(cm, __shfl_xor(cm, off, 32));
        cm = fmaxf(cm, 1e-37f);
        __syncthreads();
        A[n][p] = acc / cm;
        sA = sA + mmax + __logf(cm);
    }
    __syncthreads();

    if (!final) {
        Qout[(size_t)(blockIdx.x * 32 + p) * 32 + n] = A[n][p];
        if (n == 0) Sout[blockIdx.x * 32 + p] = sA;
        return;
    }

    if (n == 0) sgf[p] = sA;
    if (t == 0) {
        float s = 0.f;
#pragma unroll
        for (int i = 0; i < 16; ++i) s += gred[i];
        gold_s = s;
    }
    __syncthreads();
    if (t < 32) {
        float v = A[t][START_TAG] * __expf(trans[STOP_TAG * T_TAG + t]);
#pragma unroll
        for (int off = 16; off; off >>= 1) v += __shfl_xor(v, off, 32);
        if (t == 0) out[0] = sgf[START_TAG] + __logf(v) - gold_s;
    }
}

// ---------------- launch ----------------
extern "C" void kernel_launch(void* const* d_in, const int* in_sizes, int n_in,
                              void* d_out, int out_size, void* d_ws, size_t ws_size,
                              hipStream_t stream) {
    const int*   ctx   = (const int*)d_in[0];
    const float* gz    = (const float*)d_in[1];
    const int*   lab   = (const int*)d_in[2];
    const float* emb   = (const float*)d_in[3];
    const float* w1    = (const float*)d_in[4];
    const float* b1    = (const float*)d_in[5];
    const float* w2    = (const float*)d_in[6];
    const float* b2    = (const float*)d_in[7];
    const float* trans = (const float*)d_in[8];
    float* out = (float*)d_out;

    char* ws = (char*)d_ws;
    bf16_t* Xb  = (bf16_t*)(ws + 0);               // 8192*3456*2 = 56,623,104
    bf16_t* W1b = (bf16_t*)(ws + 56623104);        // 1024*3456*2 =  7,077,888
    bf16_t* Hb  = (bf16_t*)(ws + 63700992);        // 8192*1024*2 = 16,777,216
    float*  F   = (float*)(ws + 80478208);         // 8192*32*4   =  1,048,576
    float*  QT  = (float*)(ws + 81526784);         // 64*32*32*4  =    262,144
    float*  sg  = (float*)(ws + 81788928);         // 64*32*4     =      8,192
    // fold temporaries overlay the Xb region (consumed after gemm1):
    float*  Q1  = (float*)(ws + 65536);            // 16*32*32*4  =     65,536
    float*  S1  = (float*)(ws + 131072);           // 16*32*4     =      2,048

    build_x<<<S_LEN, 256, 0, stream>>>(ctx, gz, emb, Xb);
    build_w1b<<<H_DIM, 256, 0, stream>>>(w1, W1b);
    gemm1<<<dim3(S_LEN / 256, H_DIM / 128), 512, 0, stream>>>(Xb, W1b, b1, Hb);
    feats_mfma<<<S_LEN / 128, 256, 0, stream>>>(Hb, w2, b2, F);
    crfA<<<K_CHUNKS * 4, 256, 0, stream>>>(F, trans, QT, sg);
    crf_fold<<<16, 1024, 0, stream>>>(QT, sg, 4, 0, Q1, S1, trans, F, lab, out);
    crf_fold<<<1, 1024, 0, stream>>>(Q1, S1, 16, 1, nullptr, nullptr, trans, F, lab, out);
}

// Round 2
// 278.480 us; speedup vs baseline: 1.1426x; 1.1426x over previous
//
#include <hip/hip_runtime.h>

#define S_LEN 8192
#define C_CTX 21
#define E_DIM 128
#define G_DIM 36
#define H_DIM 1024
#define T_TAG 32
#define D_RAW 3444          // 21*(128+36)
#define DP 3456             // padded to multiple of 64 (54 K-tiles of 64)
#define START_TAG 30
#define STOP_TAG 31
#define NEGV -10000.0f
#define K_CHUNKS 64
#define L_CHUNK 128         // K_CHUNKS * L_CHUNK == S_LEN

typedef __bf16 bf16_t;
typedef __bf16 bf16x4 __attribute__((ext_vector_type(4)));
typedef __bf16 bf16x8 __attribute__((ext_vector_type(8)));
typedef float  f32x4  __attribute__((ext_vector_type(4)));

__device__ inline void async_copy16(const bf16_t* g, bf16_t* l) {
    __builtin_amdgcn_global_load_lds(
        (const __attribute__((address_space(1))) void*)g,
        (__attribute__((address_space(3))) void*)l, 16, 0, 0);
}

// ---------------- Phase 0: materialize padded bf16 X and W1 ----------------
// 4 cols per thread: 164 = 41 groups of 4; groups never straddle emb/gz.
__global__ void build_x(const int* __restrict__ ctx, const float* __restrict__ gz,
                        const float* __restrict__ emb, bf16_t* __restrict__ X) {
    const int s = blockIdx.x;
    for (int g = threadIdx.x; g < DP / 4; g += 256) {   // 864 groups
        float4 v = {0.f, 0.f, 0.f, 0.f};
        if (g < D_RAW / 4) {                             // 861 real groups
            const int c  = g / 41;
            const int rg = g - c * 41;                   // 0..40
            if (rg < 32) v = *(const float4*)&emb[(size_t)ctx[s * C_CTX + c] * E_DIM + rg * 4];
            else         v = *(const float4*)&gz[((size_t)s * C_CTX + c) * G_DIM + (rg - 32) * 4];
        }
        bf16x4 o = {(bf16_t)v.x, (bf16_t)v.y, (bf16_t)v.z, (bf16_t)v.w};
        *(bf16x4*)&X[(size_t)s * DP + g * 4] = o;
    }
}

__global__ void build_w1b(const float* __restrict__ w1, bf16_t* __restrict__ W) {
    const int h = blockIdx.x;
    for (int g = threadIdx.x; g < DP / 4; g += 256) {
        float4 v = {0.f, 0.f, 0.f, 0.f};
        if (g < D_RAW / 4) v = *(const float4*)&w1[(size_t)h * D_RAW + g * 4];
        bf16x4 o = {(bf16_t)v.x, (bf16_t)v.y, (bf16_t)v.z, (bf16_t)v.w};
        *(bf16x4*)&W[(size_t)h * DP + g * 4] = o;
    }
}

// ---------------- Phase 1: h = relu(X @ W1^T + b1), bf16 MFMA -------------
// 256x128 tile, BK=64, 512 threads (8 waves, 4M x 2N, 64x64 per wave).
// Faithful T3+T4 schedule (m201 template granularity): per K-tile, 2
// super-phases of {12 ds_read_b128 + 3 global_load_lds issued BEFORE a raw
// s_barrier -> setprio(1) -> 16 MFMA -> setprio(0) -> [counted vmcnt at tile
// end, never 0 mid-loop] -> s_barrier}. Triple-buffered K-tiles, prefetch
// distance 2: end-of-tile vmcnt(6) leaves the next-next tile's 6 loads in
// flight across the barrier. No sched_barrier(0), no blanket fences —
// compiler keeps its fine-grained lgkmcnt scheduling for ds_read->MFMA.
// LDS k-group swizzle kg ^ (row&7): inverse-swizzled global source + linear
// global_load_lds dest + swizzled ds_read (both-sides-or-neither).
__global__ __launch_bounds__(512) void gemm1(const bf16_t* __restrict__ X,
                                             const bf16_t* __restrict__ W,
                                             const float* __restrict__ b1,
                                             bf16_t* __restrict__ Hout) {
    __shared__ bf16_t As[3][256 * 64];   // 3 x 32 KB
    __shared__ bf16_t Bs[3][128 * 64];   // 3 x 16 KB  (total 144 KB, 1 block/CU)
    const int tid  = threadIdx.x;
    const int wave = tid >> 6, lane = tid & 63;
    const int s0 = blockIdx.x * 256, h0 = blockIdx.y * 128;
    const int wm = (wave >> 1) * 64;     // 4 wave-rows
    const int wn = (wave & 1) * 64;      // 2 wave-cols

    // staging: load l = i*512+tid -> LDS row l/8 = i*64 + (tid>>3), group tid&7
    // source k-group inverse-swizzled so that LDS[row][g] = X[row][(g^(row&7))*8..]
    const int arow = tid >> 3;                         // 0..63
    const int akg  = (tid & 7) ^ (arow & 7);
    const bf16_t* gA = X + (size_t)(s0 + arow) * DP + akg * 8;
    const bf16_t* gB = W + (size_t)(h0 + arow) * DP + akg * 8;

    const int lrow  = lane & 15;
    const int khalf = lane >> 4;         // 0..3
    const int lr7   = lrow & 7;

#define STAGE_A(buf, k0, i) async_copy16(gA + (size_t)(i) * 64 * DP + (k0), &As[buf][((i) * 512 + tid) * 8])
#define STAGE_B(buf, k0, i) async_copy16(gB + (size_t)(i) * 64 * DP + (k0), &Bs[buf][((i) * 512 + tid) * 8])

    // prologue: tiles 0 and 1 (12 loads in flight)
    STAGE_A(0, 0, 0); STAGE_A(0, 0, 1); STAGE_A(0, 0, 2); STAGE_A(0, 0, 3);
    STAGE_B(0, 0, 0); STAGE_B(0, 0, 1);
    STAGE_A(1, 64, 0); STAGE_A(1, 64, 1); STAGE_A(1, 64, 2); STAGE_A(1, 64, 3);
    STAGE_B(1, 64, 0); STAGE_B(1, 64, 1);
    asm volatile("s_waitcnt vmcnt(6)" ::: "memory");   // tile 0 landed; tile 1 in flight
    __builtin_amdgcn_s_barrier();

    f32x4 acc[4][4] = {};
    const int NT = DP / 64;              // 54
    int rb = 0;
    for (int t = 0; t < NT; ++t) {
        const int  sb = (rb == 0) ? 2 : rb - 1;   // (t+2)%3: buffer of tile t-1, reads done
        const int  k2 = (t + 2) * 64;
        const bool st = (t + 2) < NT;

#pragma unroll
        for (int sp = 0; sp < 2; ++sp) {          // super-phase = M-half (qm = sp)
            // ds-load register subtiles for this super-phase (12 x ds_read_b128)
            bf16x8 a[2][2];        // [ks][mt]
            bf16x8 b[2][2][2];     // [qn][ks][nt]
#pragma unroll
            for (int ks = 0; ks < 2; ++ks) {
                const int kgr = ((ks * 4 + khalf) ^ lr7) * 8;
#pragma unroll
                for (int mt = 0; mt < 2; ++mt)
                    a[ks][mt] = *(const bf16x8*)&As[rb][(wm + sp * 32 + mt * 16 + lrow) * 64 + kgr];
#pragma unroll
                for (int qn = 0; qn < 2; ++qn)
#pragma unroll
                    for (int nt = 0; nt < 2; ++nt)
                        b[qn][ks][nt] = *(const bf16x8*)&Bs[rb][(wn + qn * 32 + nt * 16 + lrow) * 64 + kgr];
            }
            // stage 3 of next-next tile's 6 loads (issue-early; land under MFMA)
            if (st) {
                if (sp == 0) { STAGE_A(sb, k2, 0); STAGE_A(sb, k2, 1); STAGE_B(sb, k2, 0); }
                else         { STAGE_A(sb, k2, 2); STAGE_A(sb, k2, 3); STAGE_B(sb, k2, 1); }
            }
            __builtin_amdgcn_s_barrier();         // reads + loads in flight while waiting
            __builtin_amdgcn_s_setprio(1);
#pragma unroll
            for (int ks = 0; ks < 2; ++ks)        // ks outer: 8 independent MFMA per group
#pragma unroll
                for (int qn = 0; qn < 2; ++qn)
#pragma unroll
                    for (int mt = 0; mt < 2; ++mt)
#pragma unroll
                        for (int nt = 0; nt < 2; ++nt)
                            acc[sp * 2 + mt][qn * 2 + nt] = __builtin_amdgcn_mfma_f32_16x16x32_bf16(
                                a[ks][mt], b[qn][ks][nt], acc[sp * 2 + mt][qn * 2 + nt], 0, 0, 0);
            __builtin_amdgcn_s_setprio(0);
            if (sp == 1) {
                // tile-boundary wait: next tile's 6 loads (oldest outstanding)
                // landed; newest 6 (tile t+2) stay in flight across the barrier.
                if (st)              asm volatile("s_waitcnt vmcnt(6)" ::: "memory");
                else if (t + 1 < NT) asm volatile("s_waitcnt vmcnt(0)" ::: "memory");
            }
            __builtin_amdgcn_s_barrier();
        }
        rb = (rb == 2) ? 0 : rb + 1;
    }
#undef STAGE_A
#undef STAGE_B

    const int crow = (lane >> 4) * 4;
    const int ccol = lane & 15;
#pragma unroll
    for (int nt = 0; nt < 4; ++nt) {
        const int j = h0 + wn + nt * 16 + ccol;
        const float bv = b1[j];
#pragma unroll
        for (int mt = 0; mt < 4; ++mt) {
#pragma unroll
            for (int r = 0; r < 4; ++r) {
                const int s = s0 + wm + mt * 16 + crow + r;
                const float v = acc[mt][nt][r] + bv;
                Hout[(size_t)s * H_DIM + j] = (bf16_t)fmaxf(v, 0.f);
            }
        }
    }
}

// ---------------- Phase 2: feats = H @ w2^T + b2 (fp32 out), MFMA ----------
// M=128 x N=32, BK=64 (16 iters). A via global_load_lds; B converted fp32->bf16
// in-kernel. 64-wide rows: swizzle kg ^ (row&7).
__global__ __launch_bounds__(256) void feats_mfma(const bf16_t* __restrict__ Hb,
                                                  const float* __restrict__ w2,
                                                  const float* __restrict__ b2,
                                                  float* __restrict__ F) {
    __shared__ bf16_t As[128 * 64];
    __shared__ bf16_t Bs[32 * 64];
    const int tid  = threadIdx.x;
    const int wave = tid >> 6, lane = tid & 63;
    const int s0 = blockIdx.x * 128;
    const int wm = wave * 32;

    // A staging: chunk i*256+tid -> row = i*32 + (tid>>3), kg = tid&7
    const int arow = tid >> 3;
    const int akgs = (tid & 7) ^ (arow & 7);          // (i*32+arow)&7 == arow&7
    const bf16_t* gA = Hb + (size_t)(s0 + arow) * H_DIM + akgs * 8;
    // B staging: row = tid>>3 (0..31), kg = tid&7
    const int brow = tid >> 3;
    const int bkgs = (tid & 7) ^ (brow & 7);
    const float* wp = w2 + (size_t)brow * H_DIM + bkgs * 8;
    bf16_t* lB = &Bs[tid * 8];

    const int lrow = lane & 15;

    f32x4 acc[2][2] = {};
    for (int k0 = 0; k0 < H_DIM; k0 += 64) {
#pragma unroll
        for (int i = 0; i < 4; ++i)
            async_copy16(gA + (size_t)i * 32 * H_DIM + k0, &As[(tid + i * 256) * 8]);
        const float4 x0 = *(const float4*)(wp + k0);
        const float4 x1 = *(const float4*)(wp + k0 + 4);
        bf16x8 bb = {(bf16_t)x0.x, (bf16_t)x0.y, (bf16_t)x0.z, (bf16_t)x0.w,
                     (bf16_t)x1.x, (bf16_t)x1.y, (bf16_t)x1.z, (bf16_t)x1.w};
        *(bf16x8*)lB = bb;
        __syncthreads();
#pragma unroll
        for (int ks = 0; ks < 2; ++ks) {
            const int kq = ((ks * 4 + (lane >> 4)) ^ (lrow & 7)) * 8;
            bf16x8 a[2], b[2];
#pragma unroll
            for (int mt = 0; mt < 2; ++mt)
                a[mt] = *(const bf16x8*)&As[(wm + mt * 16 + lrow) * 64 + kq];
#pragma unroll
            for (int nt = 0; nt < 2; ++nt)
                b[nt] = *(const bf16x8*)&Bs[(nt * 16 + lrow) * 64 + kq];
#pragma unroll
            for (int mt = 0; mt < 2; ++mt)
#pragma unroll
                for (int nt = 0; nt < 2; ++nt)
                    acc[mt][nt] = __builtin_amdgcn_mfma_f32_16x16x32_bf16(a[mt], b[nt], acc[mt][nt], 0, 0, 0);
        }
        __syncthreads();
    }
    const int crow = (lane >> 4) * 4;
    const int ccol = lane & 15;
#pragma unroll
    for (int nt = 0; nt < 2; ++nt) {
        const int j = nt * 16 + ccol;
        const float bv = b2[j];
#pragma unroll
        for (int mt = 0; mt < 2; ++mt) {
#pragma unroll
            for (int r = 0; r < 4; ++r) {
                const int s = s0 + wm + mt * 16 + crow + r;
                F[(size_t)s * T_TAG + j] = acc[mt][nt][r] + bv;
            }
        }
    }
}

// ---------------- CRF pass A: per-chunk matrix-chain products --------------
// v round-trips through a per-wave LDS slice (wave-lockstep => barrier-free):
// 1 ds_write + 8 broadcast ds_read_b128 per step instead of 32 bpermutes.
__global__ __launch_bounds__(256) void crfA(const float* __restrict__ F,
                                            const float* __restrict__ trans,
                                            float* __restrict__ QT,
                                            float* __restrict__ sigma) {
    __shared__ float fl[L_CHUNK * 32];
    __shared__ float vb[4][2][32];
    const int c    = blockIdx.x >> 2;
    const int tid  = threadIdx.x;
    const int wave = tid >> 6;
    const int lane = tid & 63;
    const int n    = lane & 31;
    const int pl   = lane >> 5;
    const int p    = ((blockIdx.x & 3) << 3) + (wave << 1) + pl;
    const int s0   = c * L_CHUNK;
    for (int i = tid; i < L_CHUNK * 32; i += 256) fl[i] = F[(size_t)s0 * 32 + i];
    __syncthreads();

    float et[32];
#pragma unroll
    for (int k = 0; k < 32; ++k) et[k] = __expf(trans[n * 32 + k]);

    float* vrow = &vb[wave][pl][0];
    float v  = __expf(trans[n * 32 + p] + fl[n]);
    float sg = 0.f;
    for (int s = 1; s < L_CHUNK; ++s) {
        vrow[n] = v;
        __builtin_amdgcn_s_waitcnt(0xC07F);   // lgkmcnt(0): wave-coherent LDS
        float a0 = 0.f, a1 = 0.f, a2 = 0.f, a3 = 0.f;
#pragma unroll
        for (int q = 0; q < 8; ++q) {
            const float4 wv = *(const float4*)&vrow[q * 4];
            a0 = __builtin_fmaf(et[q * 4 + 0], wv.x, a0);
            a1 = __builtin_fmaf(et[q * 4 + 1], wv.y, a1);
            a2 = __builtin_fmaf(et[q * 4 + 2], wv.z, a2);
            a3 = __builtin_fmaf(et[q * 4 + 3], wv.w, a3);
        }
        v = __expf(fl[s * 32 + n]) * ((a0 + a1) + (a2 + a3));
        if ((s & 7) == 7) {
            float m = v;
#pragma unroll
            for (int off = 16; off; off >>= 1) m = fmaxf(m, __shfl_xor(m, off, 32));
            if (m > 0.f) { v *= 1.0f / m; sg += __logf(m); }
        }
    }
    QT[(c * 32 + p) * 32 + n] = v;
    if (n == 0) sigma[c * 32 + p] = sg;
}

// ---------------- CRF pass B: parallel matrix fold ----------------
__global__ __launch_bounds__(1024) void crf_fold(const float* __restrict__ Qin,
                                                 const float* __restrict__ Sin,
                                                 const int fold, const int final,
                                                 float* __restrict__ Qout,
                                                 float* __restrict__ Sout,
                                                 const float* __restrict__ trans,
                                                 const float* __restrict__ F,
                                                 const int* __restrict__ lab,
                                                 float* __restrict__ out) {
    __shared__ float A[32][33];
    __shared__ float M[32][33];
    __shared__ float sgf[32];
    __shared__ float gred[16];
    __shared__ float gold_s;

    const int t = threadIdx.x;
    const int p = t >> 5, n = t & 31;
    const int c0 = blockIdx.x * fold;

    if (final) {
        float ga = 0.f;
        for (int s = t; s < S_LEN; s += 1024) {
            const int tg = lab[s];
            ga += F[(size_t)s * T_TAG + tg];
            const int tp = (s == 0) ? START_TAG : lab[s - 1];
            ga += trans[tg * T_TAG + tp];
        }
        if (t == 0) ga += trans[STOP_TAG * T_TAG + lab[S_LEN - 1]];
#pragma unroll
        for (int off = 32; off; off >>= 1) ga += __shfl_down(ga, off, 64);
        if ((t & 63) == 0) gred[t >> 6] = ga;
    }

    A[n][p] = Qin[(size_t)(c0 * 32 + p) * 32 + n];
    float sA = Sin[c0 * 32 + p];
    float mreg = Qin[(size_t)((c0 + 1) * 32 + p) * 32 + n];

    for (int i = 1; i < fold; ++i) {
        const float sMn = Sin[(c0 + i) * 32 + n];
        float mmax = sMn;
#pragma unroll
        for (int off = 16; off; off >>= 1) mmax = fmaxf(mmax, __shfl_xor(mmax, off, 32));
        const float sMp = Sin[(c0 + i) * 32 + p];
        __syncthreads();
        M[n][p] = mreg * __expf(sMp - mmax);
        if (i + 1 < fold) mreg = Qin[(size_t)((c0 + i + 1) * 32 + p) * 32 + n];
        __syncthreads();
        float acc = 0.f;
#pragma unroll 8
        for (int k = 0; k < 32; ++k)
            acc += M[n][k] * A[k][p];
        float cm = acc;
#pragma unroll
        for (int off = 16; off; off >>= 1) cm = fmaxf(cm, __shfl_xor(cm, off, 32));
        cm = fmaxf(cm, 1e-37f);
        __syncthreads();
        A[n][p] = acc / cm;
        sA = sA + mmax + __logf(cm);
    }
    __syncthreads();

    if (!final) {
        Qout[(size_t)(blockIdx.x * 32 + p) * 32 + n] = A[n][p];
        if (n == 0) Sout[blockIdx.x * 32 + p] = sA;
        return;
    }

    if (n == 0) sgf[p] = sA;
    if (t == 0) {
        float s = 0.f;
#pragma unroll
        for (int i = 0; i < 16; ++i) s += gred[i];
        gold_s = s;
    }
    __syncthreads();
    if (t < 32) {
        float v = A[t][START_TAG] * __expf(trans[STOP_TAG * T_TAG + t]);
#pragma unroll
        for (int off = 16; off; off >>= 1) v += __shfl_xor(v, off, 32);
        if (t == 0) out[0] = sgf[START_TAG] + __logf(v) - gold_s;
    }
}

// ---------------- launch ----------------
extern "C" void kernel_launch(void* const* d_in, const int* in_sizes, int n_in,
                              void* d_out, int out_size, void* d_ws, size_t ws_size,
                              hipStream_t stream) {
    const int*   ctx   = (const int*)d_in[0];
    const float* gz    = (const float*)d_in[1];
    const int*   lab   = (const int*)d_in[2];
    const float* emb   = (const float*)d_in[3];
    const float* w1    = (const float*)d_in[4];
    const float* b1    = (const float*)d_in[5];
    const float* w2    = (const float*)d_in[6];
    const float* b2    = (const float*)d_in[7];
    const float* trans = (const float*)d_in[8];
    float* out = (float*)d_out;

    char* ws = (char*)d_ws;
    bf16_t* Xb  = (bf16_t*)(ws + 0);               // 8192*3456*2 = 56,623,104
    bf16_t* W1b = (bf16_t*)(ws + 56623104);        // 1024*3456*2 =  7,077,888
    bf16_t* Hb  = (bf16_t*)(ws + 63700992);        // 8192*1024*2 = 16,777,216
    float*  F   = (float*)(ws + 80478208);         // 8192*32*4   =  1,048,576
    float*  QT  = (float*)(ws + 81526784);         // 64*32*32*4  =    262,144
    float*  sg  = (float*)(ws + 81788928);         // 64*32*4     =      8,192
    // fold temporaries overlay the Xb region (consumed after gemm1):
    float*  Q1  = (float*)(ws + 65536);            // 16*32*32*4  =     65,536
    float*  S1  = (float*)(ws + 131072);           // 16*32*4     =      2,048

    build_x<<<S_LEN, 256, 0, stream>>>(ctx, gz, emb, Xb);
    build_w1b<<<H_DIM, 256, 0, stream>>>(w1, W1b);
    gemm1<<<dim3(S_LEN / 256, H_DIM / 128), 512, 0, stream>>>(Xb, W1b, b1, Hb);
    feats_mfma<<<S_LEN / 128, 256, 0, stream>>>(Hb, w2, b2, F);
    crfA<<<K_CHUNKS * 4, 256, 0, stream>>>(F, trans, QT, sg);
    crf_fold<<<16, 1024, 0, stream>>>(QT, sg, 4, 0, Q1, S1, trans, F, lab, out);
    crf_fold<<<1, 1024, 0, stream>>>(Q1, S1, 16, 1, nullptr, nullptr, trans, F, lab, out);
}